// Round 7
// baseline (840.359 us; speedup 1.0000x reference)
//
#include <hip/hip_runtime.h>
#include <cfloat>

#define HH 64
#define WW 64
#define NKEYS 17
#define CCH 32
#define BG_W 10.0f

typedef unsigned long long u64;
typedef float f32x4 __attribute__((ext_vector_type(4)));

__device__ inline void nt_store4(const float4& v, float4* p) {
    __builtin_nontemporal_store(*(const f32x4*)&v, (f32x4*)p);
}

struct VI { float v; int i; };
// strict <: keeps left on ties. Call with left = lower index.
__device__ inline VI vimin(VI a, VI b) { return (b.v < a.v) ? b : a; }

__device__ inline VI row4min(const float4& v, int i0) {
    VI a = {v.x, i0}, b = {v.y, i0 + 1}, c = {v.z, i0 + 2}, d = {v.w, i0 + 3};
    return vimin(vimin(a, b), vimin(c, d));
}

// shuffle-only wave argmin (no LDS, no barrier); ties -> lower index
__device__ inline void wave_argmin(float &v, int &i) {
    #pragma unroll
    for (int off = 32; off > 0; off >>= 1) {
        float ov = __shfl_down(v, off, 64);
        int   oi = __shfl_down(i, off, 64);
        if (ov < v || (ov == v && oi < i)) { v = ov; i = oi; }
    }
}

__device__ inline u64 packvi(float v, int i) {
    // wdist >= 0 so float bits are monotone: u64 order == (value, index) lex order
    return ((u64)__float_as_uint(v) << 32) | (unsigned int)i;
}

// block argmin -> *slot (fallback path only; costs 2 barriers)
__device__ inline void block_argmin_slot(float v, int i, int tid,
                                         float* s_rv, int* s_ri, u64* slot) {
    __syncthreads();
    wave_argmin(v, i);
    if ((tid & 63) == 0) { s_rv[tid >> 6] = v; s_ri[tid >> 6] = i; }
    __syncthreads();
    if (tid == 0) {
        float bv = s_rv[0]; int bi = s_ri[0];
        for (int w2 = 1; w2 < 4; w2++) {
            float ov = s_rv[w2]; int oi = s_ri[w2];
            if (ov < bv || (ov == bv && oi < bi)) { bv = ov; bi = oi; }
        }
        *slot = packvi(bv, bi);
    }
}

// Closed-form ring weight (Chebyshev ring + border-m=1 special)
__device__ inline float ring_weight(int px, int py, int kpx, int kpy, int bxc, int byc) {
    const int adx = abs(px - kpx);
    const int ady = abs(py - kpy);
    int M = 0;
    if (adx <= 15 && ady <= adx) M = adx;
    if (ady <= 15 && adx <= ady) M = max(M, ady);
    if ((px == bxc && ady <= 1) || (py == byc && adx <= 1)) M = max(M, 1);
    return (M > 0) ? fmaf(0.25f, (float)M, 0.5f) : BG_W;
}

// 4x bilinear upsample of stripe yg from s_wd (18 rows, L=1..16 own, 0/17 halo),
// nontemporal stores of 64 fine rows, returns per-thread fine argmin partial.
// thread = (suby = tid>>6, jx = tid&63).
__device__ inline VI upsample_stripe(const float* s_wd, int bn, int yg, int tid,
                                     float* out_x4) {
    const int jx   = tid & 63;
    const int suby = tid >> 6;
    const int jxm1 = max(jx - 1, 0);
    const int jxp1 = min(jx + 1, WW - 1);
    const bool xe0 = (jx == 0);
    const bool xe1 = (jx == WW - 1);

    auto xrow = [&](int L) -> float4 {
        const float* rr = s_wd + L * WW;
        const float a  = rr[jxm1];
        const float bb = rr[jx];
        const float c  = rr[jxp1];
        float4 o;
        o.x = xe0 ? bb : fmaf(0.375f, a, 0.625f * bb);
        o.y = xe0 ? bb : fmaf(0.125f, a, 0.875f * bb);
        o.z = xe1 ? bb : fmaf(0.125f, c, 0.875f * bb);
        o.w = xe1 ? bb : fmaf(0.375f, c, 0.625f * bb);
        return o;
    };
    auto lerp4 = [](float wa, const float4& A, float wb, const float4& B) {
        float4 o;
        o.x = fmaf(wa, A.x, wb * B.x);
        o.y = fmaf(wa, A.y, wb * B.y);
        o.z = fmaf(wa, A.z, wb * B.z);
        o.w = fmaf(wa, A.w, wb * B.w);
        return o;
    };

    VI fine = {FLT_MAX, 0x7fffffff};
    float4* xo4 = (float4*)(out_x4 + (size_t)bn * (256 * 256)) + jx;

    const int jy0 = yg * 16 + suby * 4;
    const int L0  = suby * 4 + 1;
    float4 Xc = xrow(L0);
    float4 Xp = xrow(L0 - 1);   // garbage iff jy0==0 (never used then)

    #pragma unroll
    for (int q = 0; q < 4; q++) {
        const int jy = jy0 + q;
        const int L  = L0 + q;
        const float4 Xn = xrow(L + 1);   // garbage iff jy==63 (never used then)
        float4 v0, v1, v2, v3;
        if (jy == 0) { v0 = Xc; v1 = Xc; }
        else {
            v0 = lerp4(0.375f, Xp, 0.625f, Xc);
            v1 = lerp4(0.125f, Xp, 0.875f, Xc);
        }
        if (jy == HH - 1) { v2 = Xc; v3 = Xc; }
        else {
            v2 = lerp4(0.875f, Xc, 0.125f, Xn);
            v3 = lerp4(0.625f, Xc, 0.375f, Xn);
        }
        const int r0 = jy * 4;
        nt_store4(v0, &xo4[(size_t)(r0 + 0) * 64]);
        nt_store4(v1, &xo4[(size_t)(r0 + 1) * 64]);
        nt_store4(v2, &xo4[(size_t)(r0 + 2) * 64]);
        nt_store4(v3, &xo4[(size_t)(r0 + 3) * 64]);
        const int ib = r0 * 256 + 4 * jx;
        VI a0 = row4min(v0, ib);
        VI a1 = row4min(v1, ib + 256);
        VI a2 = row4min(v2, ib + 512);
        VI a3 = row4min(v3, ib + 768);
        fine = vimin(fine, vimin(vimin(a0, a1), vimin(a2, a3)));
        Xp = Xc;
        Xc = Xn;
    }
    return fine;
}

// Merged kernel, one block per (bn, y-stripe).
// __launch_bounds__(256, 8): force VGPR <= 64 -> 32 waves/CU (8 blocks/CU) so
// store-phase blocks overlap load/compute-phase blocks on the same CU.
// WP=true : wave-level argmin partials, zero reduction barriers; parts stride 32.
// WP=false: fallback (block-level partials, stride 16, fits in out_keys region).
template<bool WP>
__global__ __launch_bounds__(256, 8) void ee_merged(
    const float* __restrict__ kq,
    const float* __restrict__ mkeys,
    const int*   __restrict__ mjoints,
    float* __restrict__ out_x4,
    u64* parts)
{
    const int nb  = gridDim.x;
    const int bid = blockIdx.x;
    const int bnyg = ((nb & 7) == 0) ? ((bid & 7) * (nb >> 3) + (bid >> 3)) : bid;
    const int bn  = bnyg >> 2;
    const int yg  = bnyg & 3;
    const int b   = bn / NKEYS;
    const int tid = threadIdx.x;
    const int lane = tid & 63;
    const int wv  = tid >> 6;

    __shared__ float s_mk[CCH];
    __shared__ __align__(16) float s_wd[18 * WW];
    __shared__ float s_rv[4];
    __shared__ int   s_ri[4];

    // hoist uniform loads above the barrier (hide latency under it)
    const int kpx = mjoints[bn * 2 + 0];
    const int kpy = mjoints[bn * 2 + 1];

    if (tid < CCH) s_mk[tid] = mkeys[bn * CCH + tid];
    __syncthreads();   // only mkeys loads in flight: cheap drain

    float k2 = 0.0f;
    #pragma unroll
    for (int c = 0; c < CCH; c++) { float v = s_mk[c]; k2 += v * v; }

    const int bxc = (kpx == 0) ? 0 : ((kpx == WW - 1) ? WW - 1 : -1);
    const int byc = (kpy == 0) ? 0 : ((kpy == HH - 1) ? HH - 1 : -1);

    const float4* kq4 = (const float4*)(kq + (size_t)b * CCH * HH * WW);

    VI coarse = {FLT_MAX, 0x7fffffff};
    const int gy_base = yg * 16 - 1;

    // 288 chunks balanced across 4 waves: wave wv owns [wv*72, wv*72+72).
    // Sub-pass A: lanes 0..63 -> base+lane; sub-pass B: lanes 0..7 -> base+64+lane.
    auto do_chunk = [&](int chunk) {
        const int L  = chunk >> 4;
        const int cx = chunk & 15;
        const int gy = gy_base + L;
        if ((unsigned)gy < (unsigned)HH) {
            const int gchunk = gy * 16 + cx;
            float4 dot = make_float4(0.f, 0.f, 0.f, 0.f);
            float4 q2  = make_float4(0.f, 0.f, 0.f, 0.f);
            #pragma unroll
            for (int c = 0; c < CCH; c++) {
                float4 v = kq4[c * 1024 + gchunk];
                float  m = s_mk[c];
                dot.x += v.x * m;  dot.y += v.y * m;
                dot.z += v.z * m;  dot.w += v.w * m;
                q2.x  += v.x * v.x; q2.y += v.y * v.y;
                q2.z  += v.z * v.z; q2.w += v.w * v.w;
            }
            const int pxb = cx * 4;
            float4 w;
            w.x = sqrtf(fmaxf(q2.x + k2 - 2.0f * dot.x, 0.0f)) * ring_weight(pxb + 0, gy, kpx, kpy, bxc, byc);
            w.y = sqrtf(fmaxf(q2.y + k2 - 2.0f * dot.y, 0.0f)) * ring_weight(pxb + 1, gy, kpx, kpy, bxc, byc);
            w.z = sqrtf(fmaxf(q2.z + k2 - 2.0f * dot.z, 0.0f)) * ring_weight(pxb + 2, gy, kpx, kpy, bxc, byc);
            w.w = sqrtf(fmaxf(q2.w + k2 - 2.0f * dot.w, 0.0f)) * ring_weight(pxb + 3, gy, kpx, kpy, bxc, byc);
            ((float4*)s_wd)[chunk] = w;
            if (L >= 1 && L <= 16)
                coarse = vimin(coarse, row4min(w, gy * WW + pxb));
        }
    };
    const int base = wv * 72;
    do_chunk(base + lane);
    if (lane < 8) do_chunk(base + 64 + lane);

    if (WP) {
        // wave-level coarse partial: shuffle-only, no barrier
        float cv = coarse.v; int ci = coarse.i;
        wave_argmin(cv, ci);
        if (lane == 0) parts[(size_t)bn * 32 + yg * 4 + wv] = packvi(cv, ci);
    } else {
        block_argmin_slot(coarse.v, coarse.i, tid, s_rv, s_ri,
                          &parts[(size_t)bn * 16 + yg]);
    }

    __syncthreads();   // publish s_wd (no output stores issued yet)

    VI fine = upsample_stripe(s_wd, bn, yg, tid, out_x4);

    if (WP) {
        float fv = fine.v; int fi = fine.i;
        wave_argmin(fv, fi);
        if (lane == 0) parts[(size_t)bn * 32 + 16 + yg * 4 + wv] = packvi(fv, fi);
        // no trailing barrier: block retires with nt-stores in flight
    } else {
        block_argmin_slot(fine.v, fine.i, tid, s_rv, s_ri,
                          &parts[(size_t)bn * 16 + 4 + yg]);
    }
}

// ---------------- Finalize ----------------
// NOTE: no __restrict__ (parts may alias the out_keys region in fallback).
__global__ __launch_bounds__(64) void ee_fin(
    const float* kq,
    const float* mkeys,
    float* out_joints,
    float* out_valid,
    float* out_keys,
    const u64* parts, int pstride, int cnt, int foff)
{
    const int bn   = blockIdx.x;
    const int b    = bn / NKEYS;
    const int lane = threadIdx.x;

    u64 pc = (lane < cnt) ? parts[(size_t)bn * pstride + lane]        : ~0ull;
    u64 pf = (lane < cnt) ? parts[(size_t)bn * pstride + foff + lane] : ~0ull;
    #pragma unroll
    for (int off = 1; off <= 8; off <<= 1) {
        u64 o;
        o = __shfl_xor(pc, off, 64); if (o < pc) pc = o;
        o = __shfl_xor(pf, off, 64); if (o < pf) pf = o;
    }
    pc = __shfl(pc, 0, 64);
    pf = __shfl(pf, 0, 64);

    const float min_d = __uint_as_float((unsigned int)(pc >> 32));
    const int   cbest = (int)(pc & 0xffffffffu);

    const float mv = (lane < CCH) ? mkeys[(size_t)bn * CCH + lane] : 0.0f;
    const bool  nz = __any(mv != 0.0f);
    const bool  valid = nz && ((int)floorf(min_d) <= 5);

    float o = mv;
    if (lane < CCH && valid)
        o = kq[(size_t)(b * CCH + lane) * (HH * WW) + cbest];

    __syncthreads();   // drain loads before (possibly aliasing) stores

    if (lane < CCH) out_keys[(size_t)bn * CCH + lane] = o;
    if (lane == 0) {
        const int fi = (int)(pf & 0xffffffffu);
        out_joints[bn * 2 + 0] = (float)(valid ? (fi >> 8)  : -1);
        out_joints[bn * 2 + 1] = (float)(valid ? (fi & 255) : -1);
        out_valid[bn] = valid ? 1.0f : 0.0f;
    }
}

extern "C" void kernel_launch(void* const* d_in, const int* in_sizes, int n_in,
                              void* d_out, int out_size, void* d_ws, size_t ws_size,
                              hipStream_t stream) {
    const float* kq = (const float*)d_in[0];
    const float* mk = (const float*)d_in[1];
    const int*   mj = (const int*)d_in[2];

    const int B  = in_sizes[1] / (NKEYS * CCH);   // 64
    const int BN = B * NKEYS;                     // 1088

    float* out_f     = (float*)d_out;
    float* o_joints  = out_f;                     // B*N*2
    float* o_valid   = o_joints + BN * 2;         // B*N
    float* o_keys    = o_valid + BN;              // B*N*C
    float* o_x4      = o_keys + BN * CCH;         // B*N*256*256

    if (ws_size >= (size_t)BN * 32 * sizeof(u64)) {
        // Primary: wave-level partials in d_ws, zero reduction barriers.
        u64* parts = (u64*)d_ws;
        ee_merged<true><<<dim3(BN * 4), dim3(256), 0, stream>>>(kq, mk, mj, o_x4, parts);
        ee_fin<<<dim3(BN), dim3(64), 0, stream>>>(kq, mk, o_joints, o_valid, o_keys,
                                                  parts, 32, 16, 16);
    } else {
        // Fallback: block-level partials stashed in each bn's own out_keys slot
        // (BN*16 u64 == out_keys size exactly); ee_fin reads before overwriting.
        u64* parts = (u64*)o_keys;
        ee_merged<false><<<dim3(BN * 4), dim3(256), 0, stream>>>(kq, mk, mj, o_x4, parts);
        ee_fin<<<dim3(BN), dim3(64), 0, stream>>>(kq, mk, o_joints, o_valid, o_keys,
                                                  parts, 16, 4, 4);
    }
}

// Round 8
// 334.250 us; speedup vs baseline: 2.5142x; 2.5142x over previous
//
#include <hip/hip_runtime.h>
#include <cfloat>

#define HH 64
#define WW 64
#define NKEYS 17
#define CCH 32
#define BG_W 10.0f
#define NGRP 9   // 17 keys -> 8 pairs + 1 singleton

typedef unsigned long long u64;
typedef float f32x4 __attribute__((ext_vector_type(4)));

__device__ inline void nt_store4(const float4& v, float4* p) {
    __builtin_nontemporal_store(*(const f32x4*)&v, (f32x4*)p);
}

struct VI { float v; int i; };
// strict <: keeps left on ties. Call with left = lower index.
__device__ inline VI vimin(VI a, VI b) { return (b.v < a.v) ? b : a; }

__device__ inline VI row4min(const float4& v, int i0) {
    VI a = {v.x, i0}, b = {v.y, i0 + 1}, c = {v.z, i0 + 2}, d = {v.w, i0 + 3};
    return vimin(vimin(a, b), vimin(c, d));
}

// shuffle-only wave argmin (no LDS, no barrier); ties -> lower index
__device__ inline void wave_argmin(float &v, int &i) {
    #pragma unroll
    for (int off = 32; off > 0; off >>= 1) {
        float ov = __shfl_down(v, off, 64);
        int   oi = __shfl_down(i, off, 64);
        if (ov < v || (ov == v && oi < i)) { v = ov; i = oi; }
    }
}

__device__ inline u64 packvi(float v, int i) {
    // wdist >= 0 so float bits are monotone: u64 order == (value, index) lex order
    return ((u64)__float_as_uint(v) << 32) | (unsigned int)i;
}

// block argmin -> *slot (fallback path only; costs 2 barriers)
__device__ inline void block_argmin_slot(float v, int i, int tid,
                                         float* s_rv, int* s_ri, u64* slot) {
    __syncthreads();
    wave_argmin(v, i);
    if ((tid & 63) == 0) { s_rv[tid >> 6] = v; s_ri[tid >> 6] = i; }
    __syncthreads();
    if (tid == 0) {
        float bv = s_rv[0]; int bi = s_ri[0];
        for (int w2 = 1; w2 < 4; w2++) {
            float ov = s_rv[w2]; int oi = s_ri[w2];
            if (ov < bv || (ov == bv && oi < bi)) { bv = ov; bi = oi; }
        }
        *slot = packvi(bv, bi);
    }
}

// Closed-form ring weight (Chebyshev ring + border-m=1 special)
__device__ inline float ring_weight(int px, int py, int kpx, int kpy, int bxc, int byc) {
    const int adx = abs(px - kpx);
    const int ady = abs(py - kpy);
    int M = 0;
    if (adx <= 15 && ady <= adx) M = adx;
    if (ady <= 15 && adx <= ady) M = max(M, ady);
    if ((px == bxc && ady <= 1) || (py == byc && adx <= 1)) M = max(M, 1);
    return (M > 0) ? fmaf(0.25f, (float)M, 0.5f) : BG_W;
}

// 4x bilinear upsample of stripe yg from s_wd (18 rows, L=1..16 own, 0/17 halo),
// nontemporal stores of 64 fine rows, returns per-thread fine argmin partial.
// thread = (suby = tid>>6, jx = tid&63).
__device__ inline VI upsample_stripe(const float* s_wd, int bn, int yg, int tid,
                                     float* out_x4) {
    const int jx   = tid & 63;
    const int suby = tid >> 6;
    const int jxm1 = max(jx - 1, 0);
    const int jxp1 = min(jx + 1, WW - 1);
    const bool xe0 = (jx == 0);
    const bool xe1 = (jx == WW - 1);

    auto xrow = [&](int L) -> float4 {
        const float* rr = s_wd + L * WW;
        const float a  = rr[jxm1];
        const float bb = rr[jx];
        const float c  = rr[jxp1];
        float4 o;
        o.x = xe0 ? bb : fmaf(0.375f, a, 0.625f * bb);
        o.y = xe0 ? bb : fmaf(0.125f, a, 0.875f * bb);
        o.z = xe1 ? bb : fmaf(0.125f, c, 0.875f * bb);
        o.w = xe1 ? bb : fmaf(0.375f, c, 0.625f * bb);
        return o;
    };
    auto lerp4 = [](float wa, const float4& A, float wb, const float4& B) {
        float4 o;
        o.x = fmaf(wa, A.x, wb * B.x);
        o.y = fmaf(wa, A.y, wb * B.y);
        o.z = fmaf(wa, A.z, wb * B.z);
        o.w = fmaf(wa, A.w, wb * B.w);
        return o;
    };

    VI fine = {FLT_MAX, 0x7fffffff};
    float4* xo4 = (float4*)(out_x4 + (size_t)bn * (256 * 256)) + jx;

    const int jy0 = yg * 16 + suby * 4;
    const int L0  = suby * 4 + 1;
    float4 Xc = xrow(L0);
    float4 Xp = xrow(L0 - 1);   // garbage iff jy0==0 (never used then)

    #pragma unroll
    for (int q = 0; q < 4; q++) {
        const int jy = jy0 + q;
        const int L  = L0 + q;
        const float4 Xn = xrow(L + 1);   // garbage iff jy==63 (never used then)
        float4 v0, v1, v2, v3;
        if (jy == 0) { v0 = Xc; v1 = Xc; }
        else {
            v0 = lerp4(0.375f, Xp, 0.625f, Xc);
            v1 = lerp4(0.125f, Xp, 0.875f, Xc);
        }
        if (jy == HH - 1) { v2 = Xc; v3 = Xc; }
        else {
            v2 = lerp4(0.875f, Xc, 0.125f, Xn);
            v3 = lerp4(0.625f, Xc, 0.375f, Xn);
        }
        const int r0 = jy * 4;
        nt_store4(v0, &xo4[(size_t)(r0 + 0) * 64]);
        nt_store4(v1, &xo4[(size_t)(r0 + 1) * 64]);
        nt_store4(v2, &xo4[(size_t)(r0 + 2) * 64]);
        nt_store4(v3, &xo4[(size_t)(r0 + 3) * 64]);
        const int ib = r0 * 256 + 4 * jx;
        VI a0 = row4min(v0, ib);
        VI a1 = row4min(v1, ib + 256);
        VI a2 = row4min(v2, ib + 512);
        VI a3 = row4min(v3, ib + 768);
        fine = vimin(fine, vimin(vimin(a0, a1), vimin(a2, a3)));
        Xp = Xc;
        Xc = Xn;
    }
    return fine;
}

// Paired merged kernel: one block per (b, n-pair, y-stripe). Grid = B*9*4.
// Each kq chunk is loaded ONCE and used for TWO keys (n0, n1) -> per-output
// staging cost halves, store duty per block doubles, kq L2 reads halve.
// WP=true : wave-level argmin partials, zero reduction barriers; parts stride 32.
// WP=false: fallback (block-level partials, stride 16, fits in out_keys region).
template<bool WP>
__global__ __launch_bounds__(256) void ee_merged(
    const float* __restrict__ kq,
    const float* __restrict__ mkeys,
    const int*   __restrict__ mjoints,
    float* __restrict__ out_x4,
    u64* parts)
{
    const int nb  = gridDim.x;
    const int bid = blockIdx.x;
    const int id  = ((nb & 7) == 0) ? ((bid & 7) * (nb >> 3) + (bid >> 3)) : bid;
    const int yg  = id & 3;
    const int gb  = id >> 2;        // b*NGRP + g
    const int g   = gb % NGRP;
    const int b   = gb / NGRP;
    const bool has2 = (g < 8);
    const int n0  = 2 * g;          // g==8 -> n0=16 singleton
    const int bn0 = b * NKEYS + n0;
    const int bn1 = bn0 + 1;        // only used when has2
    const int tid = threadIdx.x;
    const int lane = tid & 63;
    const int wv  = tid >> 6;

    __shared__ __align__(16) float s_mk[2][CCH];
    __shared__ __align__(16) float s_wd0[18 * WW];
    __shared__ __align__(16) float s_wd1[18 * WW];
    __shared__ float s_rv[4];
    __shared__ int   s_ri[4];

    // hoist uniform loads above the barrier
    const int kpx0 = mjoints[bn0 * 2 + 0];
    const int kpy0 = mjoints[bn0 * 2 + 1];
    const int kpx1 = has2 ? mjoints[bn1 * 2 + 0] : 0;
    const int kpy1 = has2 ? mjoints[bn1 * 2 + 1] : 0;

    if (tid < 2 * CCH) {
        const int nn = (tid < CCH) ? 0 : 1;
        const int c  = tid & (CCH - 1);
        const int bnn = (nn && has2) ? bn1 : bn0;
        s_mk[nn][c] = mkeys[bnn * CCH + c];
    }
    __syncthreads();   // only mkeys loads in flight: cheap drain

    float k20 = 0.0f, k21 = 0.0f;
    #pragma unroll
    for (int c = 0; c < CCH; c++) {
        float v0 = s_mk[0][c]; k20 = fmaf(v0, v0, k20);
        float v1 = s_mk[1][c]; k21 = fmaf(v1, v1, k21);
    }

    const int bxc0 = (kpx0 == 0) ? 0 : ((kpx0 == WW - 1) ? WW - 1 : -1);
    const int byc0 = (kpy0 == 0) ? 0 : ((kpy0 == HH - 1) ? HH - 1 : -1);
    const int bxc1 = (kpx1 == 0) ? 0 : ((kpx1 == WW - 1) ? WW - 1 : -1);
    const int byc1 = (kpy1 == 0) ? 0 : ((kpy1 == HH - 1) ? HH - 1 : -1);

    const float4* kq4 = (const float4*)(kq + (size_t)b * CCH * HH * WW);

    VI c0 = {FLT_MAX, 0x7fffffff};
    VI c1 = {FLT_MAX, 0x7fffffff};
    const int gy_base = yg * 16 - 1;

    // 288 chunks balanced: wave wv owns [wv*72, wv*72+72).
    auto do_chunk = [&](int chunk) {
        const int L  = chunk >> 4;
        const int cx = chunk & 15;
        const int gy = gy_base + L;
        if ((unsigned)gy < (unsigned)HH) {
            const int gchunk = gy * 16 + cx;
            float4 d0 = make_float4(0.f, 0.f, 0.f, 0.f);
            float4 d1 = make_float4(0.f, 0.f, 0.f, 0.f);
            float4 q2 = make_float4(0.f, 0.f, 0.f, 0.f);
            #pragma unroll
            for (int c = 0; c < CCH; c++) {
                float4 v = kq4[c * 1024 + gchunk];
                const float m0 = s_mk[0][c];
                const float m1 = s_mk[1][c];
                d0.x = fmaf(v.x, m0, d0.x); d0.y = fmaf(v.y, m0, d0.y);
                d0.z = fmaf(v.z, m0, d0.z); d0.w = fmaf(v.w, m0, d0.w);
                d1.x = fmaf(v.x, m1, d1.x); d1.y = fmaf(v.y, m1, d1.y);
                d1.z = fmaf(v.z, m1, d1.z); d1.w = fmaf(v.w, m1, d1.w);
                q2.x = fmaf(v.x, v.x, q2.x); q2.y = fmaf(v.y, v.y, q2.y);
                q2.z = fmaf(v.z, v.z, q2.z); q2.w = fmaf(v.w, v.w, q2.w);
            }
            const int pxb = cx * 4;
            const int p0  = gy * WW + pxb;
            float4 w;
            w.x = sqrtf(fmaxf(q2.x + k20 - 2.0f * d0.x, 0.0f)) * ring_weight(pxb + 0, gy, kpx0, kpy0, bxc0, byc0);
            w.y = sqrtf(fmaxf(q2.y + k20 - 2.0f * d0.y, 0.0f)) * ring_weight(pxb + 1, gy, kpx0, kpy0, bxc0, byc0);
            w.z = sqrtf(fmaxf(q2.z + k20 - 2.0f * d0.z, 0.0f)) * ring_weight(pxb + 2, gy, kpx0, kpy0, bxc0, byc0);
            w.w = sqrtf(fmaxf(q2.w + k20 - 2.0f * d0.w, 0.0f)) * ring_weight(pxb + 3, gy, kpx0, kpy0, bxc0, byc0);
            ((float4*)s_wd0)[chunk] = w;
            if (L >= 1 && L <= 16) c0 = vimin(c0, row4min(w, p0));
            if (has2) {
                float4 u;
                u.x = sqrtf(fmaxf(q2.x + k21 - 2.0f * d1.x, 0.0f)) * ring_weight(pxb + 0, gy, kpx1, kpy1, bxc1, byc1);
                u.y = sqrtf(fmaxf(q2.y + k21 - 2.0f * d1.y, 0.0f)) * ring_weight(pxb + 1, gy, kpx1, kpy1, bxc1, byc1);
                u.z = sqrtf(fmaxf(q2.z + k21 - 2.0f * d1.z, 0.0f)) * ring_weight(pxb + 2, gy, kpx1, kpy1, bxc1, byc1);
                u.w = sqrtf(fmaxf(q2.w + k21 - 2.0f * d1.w, 0.0f)) * ring_weight(pxb + 3, gy, kpx1, kpy1, bxc1, byc1);
                ((float4*)s_wd1)[chunk] = u;
                if (L >= 1 && L <= 16) c1 = vimin(c1, row4min(u, p0));
            }
        }
    };
    const int base = wv * 72;
    do_chunk(base + lane);
    if (lane < 8) do_chunk(base + 64 + lane);

    if (WP) {
        float cv = c0.v; int ci = c0.i;
        wave_argmin(cv, ci);
        if (lane == 0) parts[(size_t)bn0 * 32 + yg * 4 + wv] = packvi(cv, ci);
        if (has2) {
            float dv = c1.v; int di = c1.i;
            wave_argmin(dv, di);
            if (lane == 0) parts[(size_t)bn1 * 32 + yg * 4 + wv] = packvi(dv, di);
        }
    } else {
        block_argmin_slot(c0.v, c0.i, tid, s_rv, s_ri, &parts[(size_t)bn0 * 16 + yg]);
        if (has2)
            block_argmin_slot(c1.v, c1.i, tid, s_rv, s_ri, &parts[(size_t)bn1 * 16 + yg]);
    }

    __syncthreads();   // publish s_wd0/s_wd1 (no output stores issued yet)

    VI f0 = upsample_stripe(s_wd0, bn0, yg, tid, out_x4);
    if (WP) {
        float fv = f0.v; int fi = f0.i;
        wave_argmin(fv, fi);
        if (lane == 0) parts[(size_t)bn0 * 32 + 16 + yg * 4 + wv] = packvi(fv, fi);
    } else {
        block_argmin_slot(f0.v, f0.i, tid, s_rv, s_ri, &parts[(size_t)bn0 * 16 + 4 + yg]);
    }

    if (has2) {
        VI f1 = upsample_stripe(s_wd1, bn1, yg, tid, out_x4);
        if (WP) {
            float fv = f1.v; int fi = f1.i;
            wave_argmin(fv, fi);
            if (lane == 0) parts[(size_t)bn1 * 32 + 16 + yg * 4 + wv] = packvi(fv, fi);
            // no trailing barrier: block retires with nt-stores in flight
        } else {
            block_argmin_slot(f1.v, f1.i, tid, s_rv, s_ri, &parts[(size_t)bn1 * 16 + 4 + yg]);
        }
    }
}

// ---------------- Finalize ----------------
// NOTE: no __restrict__ (parts may alias the out_keys region in fallback).
__global__ __launch_bounds__(64) void ee_fin(
    const float* kq,
    const float* mkeys,
    float* out_joints,
    float* out_valid,
    float* out_keys,
    const u64* parts, int pstride, int cnt, int foff)
{
    const int bn   = blockIdx.x;
    const int b    = bn / NKEYS;
    const int lane = threadIdx.x;

    u64 pc = (lane < cnt) ? parts[(size_t)bn * pstride + lane]        : ~0ull;
    u64 pf = (lane < cnt) ? parts[(size_t)bn * pstride + foff + lane] : ~0ull;
    #pragma unroll
    for (int off = 1; off <= 8; off <<= 1) {
        u64 o;
        o = __shfl_xor(pc, off, 64); if (o < pc) pc = o;
        o = __shfl_xor(pf, off, 64); if (o < pf) pf = o;
    }
    pc = __shfl(pc, 0, 64);
    pf = __shfl(pf, 0, 64);

    const float min_d = __uint_as_float((unsigned int)(pc >> 32));
    const int   cbest = (int)(pc & 0xffffffffu);

    const float mv = (lane < CCH) ? mkeys[(size_t)bn * CCH + lane] : 0.0f;
    const bool  nz = __any(mv != 0.0f);
    const bool  valid = nz && ((int)floorf(min_d) <= 5);

    float o = mv;
    if (lane < CCH && valid)
        o = kq[(size_t)(b * CCH + lane) * (HH * WW) + cbest];

    __syncthreads();   // drain loads before (possibly aliasing) stores

    if (lane < CCH) out_keys[(size_t)bn * CCH + lane] = o;
    if (lane == 0) {
        const int fi = (int)(pf & 0xffffffffu);
        out_joints[bn * 2 + 0] = (float)(valid ? (fi >> 8)  : -1);
        out_joints[bn * 2 + 1] = (float)(valid ? (fi & 255) : -1);
        out_valid[bn] = valid ? 1.0f : 0.0f;
    }
}

extern "C" void kernel_launch(void* const* d_in, const int* in_sizes, int n_in,
                              void* d_out, int out_size, void* d_ws, size_t ws_size,
                              hipStream_t stream) {
    const float* kq = (const float*)d_in[0];
    const float* mk = (const float*)d_in[1];
    const int*   mj = (const int*)d_in[2];

    const int B  = in_sizes[1] / (NKEYS * CCH);   // 64
    const int BN = B * NKEYS;                     // 1088
    const int NB = B * NGRP * 4;                  // 2304 blocks

    float* out_f     = (float*)d_out;
    float* o_joints  = out_f;                     // B*N*2
    float* o_valid   = o_joints + BN * 2;         // B*N
    float* o_keys    = o_valid + BN;              // B*N*C
    float* o_x4      = o_keys + BN * CCH;         // B*N*256*256

    if (ws_size >= (size_t)BN * 32 * sizeof(u64)) {
        // Primary: wave-level partials in d_ws, zero reduction barriers.
        u64* parts = (u64*)d_ws;
        ee_merged<true><<<dim3(NB), dim3(256), 0, stream>>>(kq, mk, mj, o_x4, parts);
        ee_fin<<<dim3(BN), dim3(64), 0, stream>>>(kq, mk, o_joints, o_valid, o_keys,
                                                  parts, 32, 16, 16);
    } else {
        // Fallback: block-level partials stashed in each bn's own out_keys slot
        // (BN*16 u64 == out_keys size exactly); ee_fin reads before overwriting.
        u64* parts = (u64*)o_keys;
        ee_merged<false><<<dim3(NB), dim3(256), 0, stream>>>(kq, mk, mj, o_x4, parts);
        ee_fin<<<dim3(BN), dim3(64), 0, stream>>>(kq, mk, o_joints, o_valid, o_keys,
                                                  parts, 16, 4, 4);
    }
}